// Round 11
// baseline (301.048 us; speedup 1.0000x reference)
//
#include <hip/hip_runtime.h>
#include <hip/hip_fp16.h>
#include <cmath>

#define N_NODES_C 50000
#define N_EDGES_C 800000
#define N_FEAT_C 128
#define N_HID_C 64
#define HEADS_C 4
#define HEAD_DIM_C 16
#define N_CLASS_C 10
#define NUM_GRAPHS_C 64
#define LOG2E_C 1.44269504088896340736f

static __device__ __forceinline__ float leaky(float x) { return x > 0.f ? x : 0.2f * x; }

// ---------------- init ----------------
__global__ void zero_kernel(int* counts, float* sums, int n) {
    int i = blockIdx.x * blockDim.x + threadIdx.x;
    if (i < n) counts[i] = 0;
    if (i < NUM_GRAPHS_C * N_HID_C) sums[i] = 0.f;
}

// count incoming edges per dst AND record each edge's arrival rank.
__global__ void count_rank_kernel(const int* __restrict__ dst, int* __restrict__ counts,
                                  int* __restrict__ rank, int E) {
    int e = blockIdx.x * blockDim.x + threadIdx.x;
    if (e < E) rank[e] = atomicAdd(&counts[dst[e]], 1);
}

// ---------------- hierarchical scan: counts -> indptr ----------------
__global__ void scan_part(const int* __restrict__ counts, int* __restrict__ bsum, int n) {
    int b = blockIdx.x, t = threadIdx.x;  // 256 threads
    int base = b * 1024 + t * 4;
    int v = 0;
    if (base + 3 < n) {
        int4 c = *(const int4*)(counts + base);
        v = c.x + c.y + c.z + c.w;
    } else {
        for (int i = 0; i < 4; i++) if (base + i < n) v += counts[base + i];
    }
    for (int off = 32; off; off >>= 1) v += __shfl_xor(v, off, 64);
    __shared__ int ws[4];
    if ((t & 63) == 0) ws[t >> 6] = v;
    __syncthreads();
    if (t == 0) bsum[b] = ws[0] + ws[1] + ws[2] + ws[3];
}

// per-block scan; block offset computed inline by reducing bsum[0..b)
__global__ void scan_block(const int* __restrict__ counts, const int* __restrict__ bsum,
                           int* __restrict__ indptr, int n, int nb) {
    int b = blockIdx.x, t = threadIdx.x;  // 256 threads
    __shared__ int boff_s;
    if (t < 64) {
        int v = (t < b && t < nb) ? bsum[t] : 0;
        for (int off = 32; off; off >>= 1) v += __shfl_xor(v, off, 64);
        if (t == 0) boff_s = v;
    }
    int base = b * 1024 + t * 4;
    int4 c = {0, 0, 0, 0};
    if (base + 3 < n) c = *(const int4*)(counts + base);
    else {
        if (base + 0 < n) c.x = counts[base + 0];
        if (base + 1 < n) c.y = counts[base + 1];
        if (base + 2 < n) c.z = counts[base + 2];
        if (base + 3 < n) c.w = counts[base + 3];
    }
    int s0 = c.x, s1 = s0 + c.y, s2 = s1 + c.z, s3 = s2 + c.w;
    int tsum = s3;
    int lane = t & 63, wv = t >> 6;
    int v = tsum;
    for (int off = 1; off < 64; off <<= 1) {
        int u = __shfl_up(v, off, 64);
        if (lane >= off) v += u;
    }
    __shared__ int wsum[4];
    if (lane == 63) wsum[wv] = v;
    __syncthreads();
    int woff = 0;
    for (int w = 0; w < wv; w++) woff += wsum[w];
    int excl = v - tsum + woff + boff_s;
    if (b == 0 && t == 0) indptr[0] = 0;
    if (base + 0 < n) indptr[base + 1] = excl + s0;
    if (base + 1 < n) indptr[base + 2] = excl + s1;
    if (base + 2 < n) indptr[base + 3] = excl + s2;
    if (base + 3 < n) indptr[base + 4] = excl + s3;
}

// scatter: position known (indptr + precomputed rank); atomicExch executes at
// the coherent point -> no 64B write-allocate per random 4B store.
__global__ void scatter_kernel(const int* __restrict__ src, const int* __restrict__ dst,
                               const int* __restrict__ indptr, const int* __restrict__ rank,
                               int* __restrict__ csr_src, int E) {
    int e = blockIdx.x * blockDim.x + threadIdx.x;
    if (e < E) {
        int pos = indptr[dst[e]] + rank[e];
        atomicExch(&csr_src[pos], src[e]);
    }
}

// ---------------- fused GEMM + attention logits (2-LDS-tile, 4x4 micro-tile) ----
// kt unroll 1 + kb unroll 2 keeps in-flight ds_reads bounded (round-6 full
// unroll caused VGPR exhaustion + scratch spill). H output stored as fp16.
template <int K>
__global__ __launch_bounds__(256, 2) void gemm_tile_kernel(
    const float* __restrict__ X, const float* __restrict__ W,
    const float* __restrict__ a_src, const float* __restrict__ a_dst,
    __half* __restrict__ H, float* __restrict__ As, float* __restrict__ Ad, int n)
{
    __shared__ float Xs[64][36];
    __shared__ float Ws[32][64];
    int tid = threadIdx.x;
    int tx = tid & 15, ty = tid >> 4;
    int base = blockIdx.x * 64;

    float acc[4][4];
#pragma unroll
    for (int i = 0; i < 4; i++)
#pragma unroll
        for (int j = 0; j < 4; j++) acc[i][j] = 0.f;

#pragma unroll 1
    for (int kt = 0; kt < K / 32; kt++) {
        if (kt > 0) __syncthreads();
        {
            int c4 = (tid & 7) * 4;
            for (int rr = tid >> 3; rr < 64; rr += 32) {
                int row = base + rr;
                float4 v = {0.f, 0.f, 0.f, 0.f};
                if (row < n) v = *(const float4*)(X + (size_t)row * K + kt * 32 + c4);
                *(float4*)(&Xs[rr][c4]) = v;
            }
        }
        {
            const float4* wsrc = (const float4*)(W + kt * 32 * 64);
            float4* wdst = (float4*)(&Ws[0][0]);
            wdst[tid] = wsrc[tid];
            wdst[tid + 256] = wsrc[tid + 256];
        }
        __syncthreads();

#pragma unroll 2
        for (int kb = 0; kb < 32; kb += 4) {
            float4 x0 = *(const float4*)(&Xs[ty * 4 + 0][kb]);
            float4 x1 = *(const float4*)(&Xs[ty * 4 + 1][kb]);
            float4 x2 = *(const float4*)(&Xs[ty * 4 + 2][kb]);
            float4 x3 = *(const float4*)(&Xs[ty * 4 + 3][kb]);
            float4 w0 = *(const float4*)(&Ws[kb + 0][tx * 4]);
            float4 w1 = *(const float4*)(&Ws[kb + 1][tx * 4]);
            float4 w2 = *(const float4*)(&Ws[kb + 2][tx * 4]);
            float4 w3 = *(const float4*)(&Ws[kb + 3][tx * 4]);
#define FMA4(i, xc, wv) \
            acc[i][0] += xc * wv.x; acc[i][1] += xc * wv.y; \
            acc[i][2] += xc * wv.z; acc[i][3] += xc * wv.w;
            FMA4(0, x0.x, w0) FMA4(0, x0.y, w1) FMA4(0, x0.z, w2) FMA4(0, x0.w, w3)
            FMA4(1, x1.x, w0) FMA4(1, x1.y, w1) FMA4(1, x1.z, w2) FMA4(1, x1.w, w3)
            FMA4(2, x2.x, w0) FMA4(2, x2.y, w1) FMA4(2, x2.z, w2) FMA4(2, x2.w, w3)
            FMA4(3, x3.x, w0) FMA4(3, x3.y, w1) FMA4(3, x3.z, w2) FMA4(3, x3.w, w3)
#undef FMA4
        }
    }

    float4 as4 = ((const float4*)a_src)[tx];
    float4 ad4 = ((const float4*)a_dst)[tx];
    int head = tx >> 2;
#pragma unroll
    for (int i = 0; i < 4; i++) {
        int node = base + ty * 4 + i;
        if (node >= n) continue;
        __half2 hlo = __floats2half2_rn(acc[i][0], acc[i][1]);
        __half2 hhi = __floats2half2_rn(acc[i][2], acc[i][3]);
        __half2* hdst = (__half2*)(&H[(size_t)node * 64 + tx * 4]);
        hdst[0] = hlo;
        hdst[1] = hhi;
        float vs = acc[i][0] * as4.x + acc[i][1] * as4.y + acc[i][2] * as4.z + acc[i][3] * as4.w;
        float vd = acc[i][0] * ad4.x + acc[i][1] * ad4.y + acc[i][2] * ad4.z + acc[i][3] * ad4.w;
        vs += __shfl_xor(vs, 1, 64); vs += __shfl_xor(vs, 2, 64);
        vd += __shfl_xor(vd, 1, 64); vd += __shfl_xor(vd, 2, 64);
        if ((tx & 3) == 0) {
            As[node * 4 + head] = vs;
            Ad[node * 4 + head] = vd;
        }
    }
}

// ---------------- fused segment-softmax + aggregation (single pass, half2) ----
// Paired-edge scheme: lanes 0-31 own cols {2lo,2lo+1} for even-slot edges,
// lanes 32-63 for odd-slot edges; combine with one shfl_xor(32) at end.
// POOL=true (layer 2): instead of writing the node row, atomicAdd the ReLU'd
// row into sums[batch[node]] -- fuses global mean-pool numerator, eliminating
// the outb round-trip (25.6MB) and the pool kernel.
template <bool POOL>
__global__ __launch_bounds__(256) void gat_aggregate(
    const __half* __restrict__ H, const float* __restrict__ As, const float* __restrict__ Ad,
    const int* __restrict__ indptr, const int* __restrict__ csr_src,
    const float* __restrict__ bias, float* __restrict__ Out,
    const int* __restrict__ batch, float* __restrict__ sums, int n)
{
    __shared__ float ebuf[4][64][4];
    __shared__ int sbuf[4][64];
    int wave = threadIdx.x >> 6, lane = threadIdx.x & 63;
    int node = blockIdx.x * 4 + wave;
    if (node >= n) return;
    int p0 = indptr[node], p1 = indptr[node + 1];
    int deg = p1 - p0;
    int half = lane >> 5, lo = lane & 31;
    int head2 = lo >> 3;  // head of cols 2lo, 2lo+1
    float2 b2 = ((const float2*)bias)[lo];

    float accx = 0.f, accy = 0.f, denom = 0.f;
    if (deg > 0) {
        float4 ad4 = ((const float4*)Ad)[node];
        const __half2* H2 = (const __half2*)H;
        for (int base = 0; base < deg; base += 64) {
            int p = p0 + base + lane;
            if (p < p1) {
                int s = csr_src[p];
                float4 as4 = ((const float4*)As)[s];
                ebuf[wave][lane][0] = exp2f(leaky(as4.x + ad4.x) * LOG2E_C);
                ebuf[wave][lane][1] = exp2f(leaky(as4.y + ad4.y) * LOG2E_C);
                ebuf[wave][lane][2] = exp2f(leaky(as4.z + ad4.z) * LOG2E_C);
                ebuf[wave][lane][3] = exp2f(leaky(as4.w + ad4.w) * LOG2E_C);
                sbuf[wave][lane] = s;
            }
            int cnt = min(64, deg - base);
            int j = 0;
            for (; j + 8 <= cnt; j += 8) {
                int j0 = j + half, j1 = j + 2 + half, j2 = j + 4 + half, j3 = j + 6 + half;
                float e0 = ebuf[wave][j0][head2];
                float e1 = ebuf[wave][j1][head2];
                float e2 = ebuf[wave][j2][head2];
                float e3 = ebuf[wave][j3][head2];
                int s0 = sbuf[wave][j0];
                int s1 = sbuf[wave][j1];
                int s2 = sbuf[wave][j2];
                int s3 = sbuf[wave][j3];
                __half2 h0 = H2[s0 * 32 + lo];
                __half2 h1 = H2[s1 * 32 + lo];
                __half2 h2 = H2[s2 * 32 + lo];
                __half2 h3 = H2[s3 * 32 + lo];
                denom += (e0 + e1) + (e2 + e3);
                accx += e0 * __low2float(h0);  accy += e0 * __high2float(h0);
                accx += e1 * __low2float(h1);  accy += e1 * __high2float(h1);
                accx += e2 * __low2float(h2);  accy += e2 * __high2float(h2);
                accx += e3 * __low2float(h3);  accy += e3 * __high2float(h3);
            }
            for (; j < cnt; j += 2) {
                int jA = j + half;
                if (jA < cnt) {
                    float e = ebuf[wave][jA][head2];
                    int s = sbuf[wave][jA];
                    __half2 h = H2[s * 32 + lo];
                    denom += e;
                    accx += e * __low2float(h);
                    accy += e * __high2float(h);
                }
            }
        }
        accx += __shfl_xor(accx, 32, 64);
        accy += __shfl_xor(accy, 32, 64);
        denom += __shfl_xor(denom, 32, 64);
    }
    if (half == 0) {
        float inv = (deg > 0) ? 1.f / (denom + 1e-16f) : 0.f;
        float2 v;
        v.x = fmaxf(accx * inv + b2.x, 0.f);
        v.y = fmaxf(accy * inv + b2.y, 0.f);
        if (POOL) {
            int g = batch[node];
            atomicAdd(&sums[g * 64 + lo * 2 + 0], v.x);
            atomicAdd(&sums[g * 64 + lo * 2 + 1], v.y);
        } else {
            *(float2*)(&Out[(size_t)node * 64 + lo * 2]) = v;
        }
    }
}

// ---------------- final FC (per-graph counts via binary search on sorted batch) --
__global__ void fc_kernel(const float* __restrict__ sums, const int* __restrict__ batch,
                          const float* __restrict__ fcW, const float* __restrict__ fcb,
                          float* __restrict__ out, int n)
{
    __shared__ int lower[NUM_GRAPHS_C + 1];
    int t = threadIdx.x;
    if (t <= NUM_GRAPHS_C) {
        int lo = 0, hi = n;
        while (lo < hi) {
            int mid = (lo + hi) >> 1;
            if (batch[mid] < t) lo = mid + 1; else hi = mid;
        }
        lower[t] = lo;
    }
    __syncthreads();
    if (t >= NUM_GRAPHS_C * N_CLASS_C) return;
    int g = t / N_CLASS_C, c = t % N_CLASS_C;
    float cnt = fmaxf((float)(lower[g + 1] - lower[g]), 1.f);
    float inv = 1.f / cnt;
    float acc = fcb[c];
    for (int k = 0; k < 64; k++)
        acc += (sums[g * 64 + k] * inv) * fcW[k * N_CLASS_C + c];
    out[g * N_CLASS_C + c] = acc;
}

extern "C" void kernel_launch(void* const* d_in, const int* in_sizes, int n_in,
                              void* d_out, int out_size, void* d_ws, size_t ws_size,
                              hipStream_t stream) {
    const float* feat = (const float*)d_in[0];
    const float* W1   = (const float*)d_in[1];
    const float* a1s  = (const float*)d_in[2];
    const float* a1d  = (const float*)d_in[3];
    const float* b1   = (const float*)d_in[4];
    const float* W2   = (const float*)d_in[5];
    const float* a2s  = (const float*)d_in[6];
    const float* a2d  = (const float*)d_in[7];
    const float* b2   = (const float*)d_in[8];
    const float* fcW  = (const float*)d_in[9];
    const float* fcb  = (const float*)d_in[10];
    const int* eidx   = (const int*)d_in[11];
    const int* batch  = (const int*)d_in[12];

    const int N = N_NODES_C;
    const int E = N_EDGES_C;
    const int* src = eidx;
    const int* dst = eidx + E;

    char* ws = (char*)d_ws;
    size_t off = 0;
    auto alloc = [&](size_t bytes) -> void* {
        void* p = ws + off;
        off += (bytes + 255) & ~(size_t)255;
        return p;
    };
    __half* h      = (__half*)alloc((size_t)N * 64 * 2);
    float* outb    = (float*)alloc((size_t)N * 64 * 4);
    float* As      = (float*)alloc((size_t)N * 4 * 4);
    float* Ad      = (float*)alloc((size_t)N * 4 * 4);
    int*   indptr  = (int*)alloc((size_t)(N + 1) * 4);
    int*   counts  = (int*)alloc((size_t)N * 4);
    int*   rank    = (int*)alloc((size_t)E * 4);
    int*   csr_src = (int*)alloc((size_t)E * 4);
    int*   bsum    = (int*)alloc(64 * 4);
    float* sums    = (float*)alloc((size_t)NUM_GRAPHS_C * 64 * 4);

    const int NB = (N + 1023) / 1024;  // 49

    // CSR build (graph identical for both layers)
    zero_kernel<<<(N + 255) / 256, 256, 0, stream>>>(counts, sums, N);
    count_rank_kernel<<<(E + 255) / 256, 256, 0, stream>>>(dst, counts, rank, E);
    scan_part<<<NB, 256, 0, stream>>>(counts, bsum, N);
    scan_block<<<NB, 256, 0, stream>>>(counts, bsum, indptr, N, NB);
    scatter_kernel<<<(E + 255) / 256, 256, 0, stream>>>(src, dst, indptr, rank, csr_src, E);

    const int GEMM_BLOCKS = (N + 63) / 64;  // 782
    const int AGG_BLOCKS = (N + 3) / 4;

    // layer 1
    gemm_tile_kernel<N_FEAT_C><<<GEMM_BLOCKS, 256, 0, stream>>>(feat, W1, a1s, a1d, h, As, Ad, N);
    gat_aggregate<false><<<AGG_BLOCKS, 256, 0, stream>>>(h, As, Ad, indptr, csr_src, b1, outb, batch, sums, N);
    // layer 2 (pooling fused into the aggregate epilogue)
    gemm_tile_kernel<N_HID_C><<<GEMM_BLOCKS, 256, 0, stream>>>(outb, W2, a2s, a2d, h, As, Ad, N);
    gat_aggregate<true><<<AGG_BLOCKS, 256, 0, stream>>>(h, As, Ad, indptr, csr_src, b2, nullptr, batch, sums, N);

    // fc (per-graph counts via binary search on the sorted batch vector)
    fc_kernel<<<1, 1024, 0, stream>>>(sums, batch, fcW, fcb, (float*)d_out, N);
}

// Round 12
// 190.019 us; speedup vs baseline: 1.5843x; 1.5843x over previous
//
#include <hip/hip_runtime.h>
#include <hip/hip_fp16.h>
#include <cmath>

#define N_NODES_C 50000
#define N_EDGES_C 800000
#define N_FEAT_C 128
#define N_HID_C 64
#define HEADS_C 4
#define HEAD_DIM_C 16
#define N_CLASS_C 10
#define NUM_GRAPHS_C 64
#define LOG2E_C 1.44269504088896340736f

static __device__ __forceinline__ float leaky(float x) { return x > 0.f ? x : 0.2f * x; }

// ---------------- init ----------------
__global__ void zero_kernel(int* counts, float* sums, int n) {
    int i = blockIdx.x * blockDim.x + threadIdx.x;
    if (i < n) counts[i] = 0;
    if (i < NUM_GRAPHS_C * N_HID_C) sums[i] = 0.f;
}

// count incoming edges per dst AND record each edge's arrival rank.
__global__ void count_rank_kernel(const int* __restrict__ dst, int* __restrict__ counts,
                                  int* __restrict__ rank, int E) {
    int e = blockIdx.x * blockDim.x + threadIdx.x;
    if (e < E) rank[e] = atomicAdd(&counts[dst[e]], 1);
}

// ---------------- hierarchical scan: counts -> indptr ----------------
__global__ void scan_part(const int* __restrict__ counts, int* __restrict__ bsum, int n) {
    int b = blockIdx.x, t = threadIdx.x;  // 256 threads
    int base = b * 1024 + t * 4;
    int v = 0;
    if (base + 3 < n) {
        int4 c = *(const int4*)(counts + base);
        v = c.x + c.y + c.z + c.w;
    } else {
        for (int i = 0; i < 4; i++) if (base + i < n) v += counts[base + i];
    }
    for (int off = 32; off; off >>= 1) v += __shfl_xor(v, off, 64);
    __shared__ int ws[4];
    if ((t & 63) == 0) ws[t >> 6] = v;
    __syncthreads();
    if (t == 0) bsum[b] = ws[0] + ws[1] + ws[2] + ws[3];
}

// per-block scan; block offset computed inline by reducing bsum[0..b)
__global__ void scan_block(const int* __restrict__ counts, const int* __restrict__ bsum,
                           int* __restrict__ indptr, int n, int nb) {
    int b = blockIdx.x, t = threadIdx.x;  // 256 threads
    __shared__ int boff_s;
    if (t < 64) {
        int v = (t < b && t < nb) ? bsum[t] : 0;
        for (int off = 32; off; off >>= 1) v += __shfl_xor(v, off, 64);
        if (t == 0) boff_s = v;
    }
    int base = b * 1024 + t * 4;
    int4 c = {0, 0, 0, 0};
    if (base + 3 < n) c = *(const int4*)(counts + base);
    else {
        if (base + 0 < n) c.x = counts[base + 0];
        if (base + 1 < n) c.y = counts[base + 1];
        if (base + 2 < n) c.z = counts[base + 2];
        if (base + 3 < n) c.w = counts[base + 3];
    }
    int s0 = c.x, s1 = s0 + c.y, s2 = s1 + c.z, s3 = s2 + c.w;
    int tsum = s3;
    int lane = t & 63, wv = t >> 6;
    int v = tsum;
    for (int off = 1; off < 64; off <<= 1) {
        int u = __shfl_up(v, off, 64);
        if (lane >= off) v += u;
    }
    __shared__ int wsum[4];
    if (lane == 63) wsum[wv] = v;
    __syncthreads();
    int woff = 0;
    for (int w = 0; w < wv; w++) woff += wsum[w];
    int excl = v - tsum + woff + boff_s;
    if (b == 0 && t == 0) indptr[0] = 0;
    if (base + 0 < n) indptr[base + 1] = excl + s0;
    if (base + 1 < n) indptr[base + 2] = excl + s1;
    if (base + 2 < n) indptr[base + 3] = excl + s2;
    if (base + 3 < n) indptr[base + 4] = excl + s3;
}

// scatter: position known (indptr + precomputed rank); atomicExch executes at
// the coherent point -> no 64B write-allocate per random 4B store.
__global__ void scatter_kernel(const int* __restrict__ src, const int* __restrict__ dst,
                               const int* __restrict__ indptr, const int* __restrict__ rank,
                               int* __restrict__ csr_src, int E) {
    int e = blockIdx.x * blockDim.x + threadIdx.x;
    if (e < E) {
        int pos = indptr[dst[e]] + rank[e];
        atomicExch(&csr_src[pos], src[e]);
    }
}

// ---------------- fused GEMM + attention logits (2-LDS-tile, 4x4 micro-tile) ----
// kt unroll 1 + kb unroll 2 keeps in-flight ds_reads bounded (round-6 full
// unroll caused VGPR exhaustion + scratch spill). H output stored as fp16.
template <int K>
__global__ __launch_bounds__(256, 2) void gemm_tile_kernel(
    const float* __restrict__ X, const float* __restrict__ W,
    const float* __restrict__ a_src, const float* __restrict__ a_dst,
    __half* __restrict__ H, float* __restrict__ As, float* __restrict__ Ad, int n)
{
    __shared__ float Xs[64][36];
    __shared__ float Ws[32][64];
    int tid = threadIdx.x;
    int tx = tid & 15, ty = tid >> 4;
    int base = blockIdx.x * 64;

    float acc[4][4];
#pragma unroll
    for (int i = 0; i < 4; i++)
#pragma unroll
        for (int j = 0; j < 4; j++) acc[i][j] = 0.f;

#pragma unroll 1
    for (int kt = 0; kt < K / 32; kt++) {
        if (kt > 0) __syncthreads();
        {
            int c4 = (tid & 7) * 4;
            for (int rr = tid >> 3; rr < 64; rr += 32) {
                int row = base + rr;
                float4 v = {0.f, 0.f, 0.f, 0.f};
                if (row < n) v = *(const float4*)(X + (size_t)row * K + kt * 32 + c4);
                *(float4*)(&Xs[rr][c4]) = v;
            }
        }
        {
            const float4* wsrc = (const float4*)(W + kt * 32 * 64);
            float4* wdst = (float4*)(&Ws[0][0]);
            wdst[tid] = wsrc[tid];
            wdst[tid + 256] = wsrc[tid + 256];
        }
        __syncthreads();

#pragma unroll 2
        for (int kb = 0; kb < 32; kb += 4) {
            float4 x0 = *(const float4*)(&Xs[ty * 4 + 0][kb]);
            float4 x1 = *(const float4*)(&Xs[ty * 4 + 1][kb]);
            float4 x2 = *(const float4*)(&Xs[ty * 4 + 2][kb]);
            float4 x3 = *(const float4*)(&Xs[ty * 4 + 3][kb]);
            float4 w0 = *(const float4*)(&Ws[kb + 0][tx * 4]);
            float4 w1 = *(const float4*)(&Ws[kb + 1][tx * 4]);
            float4 w2 = *(const float4*)(&Ws[kb + 2][tx * 4]);
            float4 w3 = *(const float4*)(&Ws[kb + 3][tx * 4]);
#define FMA4(i, xc, wv) \
            acc[i][0] += xc * wv.x; acc[i][1] += xc * wv.y; \
            acc[i][2] += xc * wv.z; acc[i][3] += xc * wv.w;
            FMA4(0, x0.x, w0) FMA4(0, x0.y, w1) FMA4(0, x0.z, w2) FMA4(0, x0.w, w3)
            FMA4(1, x1.x, w0) FMA4(1, x1.y, w1) FMA4(1, x1.z, w2) FMA4(1, x1.w, w3)
            FMA4(2, x2.x, w0) FMA4(2, x2.y, w1) FMA4(2, x2.z, w2) FMA4(2, x2.w, w3)
            FMA4(3, x3.x, w0) FMA4(3, x3.y, w1) FMA4(3, x3.z, w2) FMA4(3, x3.w, w3)
#undef FMA4
        }
    }

    float4 as4 = ((const float4*)a_src)[tx];
    float4 ad4 = ((const float4*)a_dst)[tx];
    int head = tx >> 2;
#pragma unroll
    for (int i = 0; i < 4; i++) {
        int node = base + ty * 4 + i;
        if (node >= n) continue;
        __half2 hlo = __floats2half2_rn(acc[i][0], acc[i][1]);
        __half2 hhi = __floats2half2_rn(acc[i][2], acc[i][3]);
        __half2* hdst = (__half2*)(&H[(size_t)node * 64 + tx * 4]);
        hdst[0] = hlo;
        hdst[1] = hhi;
        float vs = acc[i][0] * as4.x + acc[i][1] * as4.y + acc[i][2] * as4.z + acc[i][3] * as4.w;
        float vd = acc[i][0] * ad4.x + acc[i][1] * ad4.y + acc[i][2] * ad4.z + acc[i][3] * ad4.w;
        vs += __shfl_xor(vs, 1, 64); vs += __shfl_xor(vs, 2, 64);
        vd += __shfl_xor(vd, 1, 64); vd += __shfl_xor(vd, 2, 64);
        if ((tx & 3) == 0) {
            As[node * 4 + head] = vs;
            Ad[node * 4 + head] = vd;
        }
    }
}

// ---------------- fused segment-softmax + aggregation (single pass, half2) ----
// Paired-edge scheme: lanes 0-31 own cols {2lo,2lo+1} for even-slot edges,
// lanes 32-63 for odd-slot edges; combine with one shfl_xor(32) at end.
// (Round-11 lesson: do NOT fuse pooling here -- 3.2M atomicAdds into 4096
// addresses serialize at the coherent point, +100us. Write Out; the separate
// run-length pool kernel does ~200K atomics.)
__global__ __launch_bounds__(256) void gat_aggregate(
    const __half* __restrict__ H, const float* __restrict__ As, const float* __restrict__ Ad,
    const int* __restrict__ indptr, const int* __restrict__ csr_src,
    const float* __restrict__ bias, float* __restrict__ Out, int n)
{
    __shared__ float ebuf[4][64][4];
    __shared__ int sbuf[4][64];
    int wave = threadIdx.x >> 6, lane = threadIdx.x & 63;
    int node = blockIdx.x * 4 + wave;
    if (node >= n) return;
    int p0 = indptr[node], p1 = indptr[node + 1];
    int deg = p1 - p0;
    int half = lane >> 5, lo = lane & 31;
    int head2 = lo >> 3;  // head of cols 2lo, 2lo+1
    float2 b2 = ((const float2*)bias)[lo];
    if (deg == 0) {
        if (half == 0) {
            float2 v = {fmaxf(b2.x, 0.f), fmaxf(b2.y, 0.f)};
            *(float2*)(&Out[(size_t)node * 64 + lo * 2]) = v;
        }
        return;
    }
    float4 ad4 = ((const float4*)Ad)[node];
    const __half2* H2 = (const __half2*)H;

    float accx = 0.f, accy = 0.f, denom = 0.f;
    for (int base = 0; base < deg; base += 64) {
        int p = p0 + base + lane;
        if (p < p1) {
            int s = csr_src[p];
            float4 as4 = ((const float4*)As)[s];
            ebuf[wave][lane][0] = exp2f(leaky(as4.x + ad4.x) * LOG2E_C);
            ebuf[wave][lane][1] = exp2f(leaky(as4.y + ad4.y) * LOG2E_C);
            ebuf[wave][lane][2] = exp2f(leaky(as4.z + ad4.z) * LOG2E_C);
            ebuf[wave][lane][3] = exp2f(leaky(as4.w + ad4.w) * LOG2E_C);
            sbuf[wave][lane] = s;
        }
        int cnt = min(64, deg - base);
        int j = 0;
        for (; j + 8 <= cnt; j += 8) {
            int j0 = j + half, j1 = j + 2 + half, j2 = j + 4 + half, j3 = j + 6 + half;
            float e0 = ebuf[wave][j0][head2];
            float e1 = ebuf[wave][j1][head2];
            float e2 = ebuf[wave][j2][head2];
            float e3 = ebuf[wave][j3][head2];
            int s0 = sbuf[wave][j0];
            int s1 = sbuf[wave][j1];
            int s2 = sbuf[wave][j2];
            int s3 = sbuf[wave][j3];
            __half2 h0 = H2[s0 * 32 + lo];
            __half2 h1 = H2[s1 * 32 + lo];
            __half2 h2 = H2[s2 * 32 + lo];
            __half2 h3 = H2[s3 * 32 + lo];
            denom += (e0 + e1) + (e2 + e3);
            accx += e0 * __low2float(h0);  accy += e0 * __high2float(h0);
            accx += e1 * __low2float(h1);  accy += e1 * __high2float(h1);
            accx += e2 * __low2float(h2);  accy += e2 * __high2float(h2);
            accx += e3 * __low2float(h3);  accy += e3 * __high2float(h3);
        }
        for (; j < cnt; j += 2) {
            int jA = j + half;
            if (jA < cnt) {
                float e = ebuf[wave][jA][head2];
                int s = sbuf[wave][jA];
                __half2 h = H2[s * 32 + lo];
                denom += e;
                accx += e * __low2float(h);
                accy += e * __high2float(h);
            }
        }
    }
    accx += __shfl_xor(accx, 32, 64);
    accy += __shfl_xor(accy, 32, 64);
    denom += __shfl_xor(denom, 32, 64);
    if (half == 0) {
        float inv = 1.f / (denom + 1e-16f);
        float2 v;
        v.x = fmaxf(accx * inv + b2.x, 0.f);
        v.y = fmaxf(accy * inv + b2.y, 0.f);
        *(float2*)(&Out[(size_t)node * 64 + lo * 2]) = v;
    }
}

// ---------------- pooling (run-length compressed atomics over sorted batch) --
__global__ void pool_kernel(const float* __restrict__ X, const int* __restrict__ batch,
                            float* __restrict__ sums, int n)
{
    int gw = (blockIdx.x * blockDim.x + threadIdx.x) >> 6;
    int lane = threadIdx.x & 63;
    int base = gw * 16;
    if (base >= n) return;
    int end = min(base + 16, n);
    int curg = batch[base];
    float acc = 0.f;
    for (int i = base; i < end; i++) {
        int g = batch[i];
        if (g != curg) {
            atomicAdd(&sums[curg * 64 + lane], acc);
            acc = 0.f; curg = g;
        }
        acc += X[(size_t)i * 64 + lane];
    }
    atomicAdd(&sums[curg * 64 + lane], acc);
}

// ---------------- final FC (per-graph counts via binary search on sorted batch) --
__global__ void fc_kernel(const float* __restrict__ sums, const int* __restrict__ batch,
                          const float* __restrict__ fcW, const float* __restrict__ fcb,
                          float* __restrict__ out, int n)
{
    __shared__ int lower[NUM_GRAPHS_C + 1];
    int t = threadIdx.x;
    if (t <= NUM_GRAPHS_C) {
        int lo = 0, hi = n;
        while (lo < hi) {
            int mid = (lo + hi) >> 1;
            if (batch[mid] < t) lo = mid + 1; else hi = mid;
        }
        lower[t] = lo;
    }
    __syncthreads();
    if (t >= NUM_GRAPHS_C * N_CLASS_C) return;
    int g = t / N_CLASS_C, c = t % N_CLASS_C;
    float cnt = fmaxf((float)(lower[g + 1] - lower[g]), 1.f);
    float inv = 1.f / cnt;
    float acc = fcb[c];
    for (int k = 0; k < 64; k++)
        acc += (sums[g * 64 + k] * inv) * fcW[k * N_CLASS_C + c];
    out[g * N_CLASS_C + c] = acc;
}

extern "C" void kernel_launch(void* const* d_in, const int* in_sizes, int n_in,
                              void* d_out, int out_size, void* d_ws, size_t ws_size,
                              hipStream_t stream) {
    const float* feat = (const float*)d_in[0];
    const float* W1   = (const float*)d_in[1];
    const float* a1s  = (const float*)d_in[2];
    const float* a1d  = (const float*)d_in[3];
    const float* b1   = (const float*)d_in[4];
    const float* W2   = (const float*)d_in[5];
    const float* a2s  = (const float*)d_in[6];
    const float* a2d  = (const float*)d_in[7];
    const float* b2   = (const float*)d_in[8];
    const float* fcW  = (const float*)d_in[9];
    const float* fcb  = (const float*)d_in[10];
    const int* eidx   = (const int*)d_in[11];
    const int* batch  = (const int*)d_in[12];

    const int N = N_NODES_C;
    const int E = N_EDGES_C;
    const int* src = eidx;
    const int* dst = eidx + E;

    char* ws = (char*)d_ws;
    size_t off = 0;
    auto alloc = [&](size_t bytes) -> void* {
        void* p = ws + off;
        off += (bytes + 255) & ~(size_t)255;
        return p;
    };
    __half* h      = (__half*)alloc((size_t)N * 64 * 2);
    float* outb    = (float*)alloc((size_t)N * 64 * 4);
    float* As      = (float*)alloc((size_t)N * 4 * 4);
    float* Ad      = (float*)alloc((size_t)N * 4 * 4);
    int*   indptr  = (int*)alloc((size_t)(N + 1) * 4);
    int*   counts  = (int*)alloc((size_t)N * 4);
    int*   rank    = (int*)alloc((size_t)E * 4);
    int*   csr_src = (int*)alloc((size_t)E * 4);
    int*   bsum    = (int*)alloc(64 * 4);
    float* sums    = (float*)alloc((size_t)NUM_GRAPHS_C * 64 * 4);

    const int NB = (N + 1023) / 1024;  // 49

    // CSR build (graph identical for both layers)
    zero_kernel<<<(N + 255) / 256, 256, 0, stream>>>(counts, sums, N);
    count_rank_kernel<<<(E + 255) / 256, 256, 0, stream>>>(dst, counts, rank, E);
    scan_part<<<NB, 256, 0, stream>>>(counts, bsum, N);
    scan_block<<<NB, 256, 0, stream>>>(counts, bsum, indptr, N, NB);
    scatter_kernel<<<(E + 255) / 256, 256, 0, stream>>>(src, dst, indptr, rank, csr_src, E);

    const int GEMM_BLOCKS = (N + 63) / 64;  // 782
    const int AGG_BLOCKS = (N + 3) / 4;

    // layer 1
    gemm_tile_kernel<N_FEAT_C><<<GEMM_BLOCKS, 256, 0, stream>>>(feat, W1, a1s, a1d, h, As, Ad, N);
    gat_aggregate<<<AGG_BLOCKS, 256, 0, stream>>>(h, As, Ad, indptr, csr_src, b1, outb, N);
    // layer 2
    gemm_tile_kernel<N_HID_C><<<GEMM_BLOCKS, 256, 0, stream>>>(outb, W2, a2s, a2d, h, As, Ad, N);
    gat_aggregate<<<AGG_BLOCKS, 256, 0, stream>>>(h, As, Ad, indptr, csr_src, b2, outb, N);

    // pool + fc (counts via binary search on the sorted batch vector)
    int pool_waves = (N + 15) / 16;
    pool_kernel<<<(pool_waves * 64 + 255) / 256, 256, 0, stream>>>(outb, batch, sums, N);
    fc_kernel<<<1, 1024, 0, stream>>>(sums, batch, fcW, fcb, (float*)d_out, N);
}

// Round 13
// 173.828 us; speedup vs baseline: 1.7319x; 1.0931x over previous
//
#include <hip/hip_runtime.h>
#include <hip/hip_fp16.h>
#include <cmath>

#define N_NODES_C 50000
#define N_EDGES_C 800000
#define N_FEAT_C 128
#define N_HID_C 64
#define HEADS_C 4
#define HEAD_DIM_C 16
#define N_CLASS_C 10
#define NUM_GRAPHS_C 64
#define LOG2E_C 1.44269504088896340736f

static __device__ __forceinline__ float leaky(float x) { return x > 0.f ? x : 0.2f * x; }

// ---------------- init ----------------
__global__ void zero_kernel(int* counts, float* sums, int n) {
    int i = blockIdx.x * blockDim.x + threadIdx.x;
    if (i < n) counts[i] = 0;
    if (i < NUM_GRAPHS_C * N_HID_C) sums[i] = 0.f;
}

// count incoming edges per dst AND record each edge's arrival rank.
__global__ void count_rank_kernel(const int* __restrict__ dst, int* __restrict__ counts,
                                  int* __restrict__ rank, int E) {
    int e = blockIdx.x * blockDim.x + threadIdx.x;
    if (e < E) rank[e] = atomicAdd(&counts[dst[e]], 1);
}

// ---------------- hierarchical scan: counts -> indptr ----------------
__global__ void scan_part(const int* __restrict__ counts, int* __restrict__ bsum, int n) {
    int b = blockIdx.x, t = threadIdx.x;  // 256 threads
    int base = b * 1024 + t * 4;
    int v = 0;
    if (base + 3 < n) {
        int4 c = *(const int4*)(counts + base);
        v = c.x + c.y + c.z + c.w;
    } else {
        for (int i = 0; i < 4; i++) if (base + i < n) v += counts[base + i];
    }
    for (int off = 32; off; off >>= 1) v += __shfl_xor(v, off, 64);
    __shared__ int ws[4];
    if ((t & 63) == 0) ws[t >> 6] = v;
    __syncthreads();
    if (t == 0) bsum[b] = ws[0] + ws[1] + ws[2] + ws[3];
}

// per-block scan; block offset computed inline by reducing bsum[0..b)
__global__ void scan_block(const int* __restrict__ counts, const int* __restrict__ bsum,
                           int* __restrict__ indptr, int n, int nb) {
    int b = blockIdx.x, t = threadIdx.x;  // 256 threads
    __shared__ int boff_s;
    if (t < 64) {
        int v = (t < b && t < nb) ? bsum[t] : 0;
        for (int off = 32; off; off >>= 1) v += __shfl_xor(v, off, 64);
        if (t == 0) boff_s = v;
    }
    int base = b * 1024 + t * 4;
    int4 c = {0, 0, 0, 0};
    if (base + 3 < n) c = *(const int4*)(counts + base);
    else {
        if (base + 0 < n) c.x = counts[base + 0];
        if (base + 1 < n) c.y = counts[base + 1];
        if (base + 2 < n) c.z = counts[base + 2];
        if (base + 3 < n) c.w = counts[base + 3];
    }
    int s0 = c.x, s1 = s0 + c.y, s2 = s1 + c.z, s3 = s2 + c.w;
    int tsum = s3;
    int lane = t & 63, wv = t >> 6;
    int v = tsum;
    for (int off = 1; off < 64; off <<= 1) {
        int u = __shfl_up(v, off, 64);
        if (lane >= off) v += u;
    }
    __shared__ int wsum[4];
    if (lane == 63) wsum[wv] = v;
    __syncthreads();
    int woff = 0;
    for (int w = 0; w < wv; w++) woff += wsum[w];
    int excl = v - tsum + woff + boff_s;
    if (b == 0 && t == 0) indptr[0] = 0;
    if (base + 0 < n) indptr[base + 1] = excl + s0;
    if (base + 1 < n) indptr[base + 2] = excl + s1;
    if (base + 2 < n) indptr[base + 3] = excl + s2;
    if (base + 3 < n) indptr[base + 4] = excl + s3;
}

// ---------------- GEMM tile body (shared by both layers) ----------------
// 2-LDS-tile, 4x4 micro-tile. kt unroll 1 + kb unroll 2 keeps in-flight
// ds_reads bounded (round-6 full unroll caused VGPR exhaustion + spill).
// H stored fp16; As/Ad logits from fp32 acc via 4-lane shfl reduce.
template <int K>
static __device__ __forceinline__ void gemm_tile_body(
    const float* __restrict__ X, const float* __restrict__ W,
    const float* __restrict__ a_src, const float* __restrict__ a_dst,
    __half* __restrict__ H, float* __restrict__ As, float* __restrict__ Ad,
    int n, int blk, float (*Xs)[36], float (*Ws)[64])
{
    int tid = threadIdx.x;
    int tx = tid & 15, ty = tid >> 4;
    int base = blk * 64;

    float acc[4][4];
#pragma unroll
    for (int i = 0; i < 4; i++)
#pragma unroll
        for (int j = 0; j < 4; j++) acc[i][j] = 0.f;

#pragma unroll 1
    for (int kt = 0; kt < K / 32; kt++) {
        if (kt > 0) __syncthreads();
        {
            int c4 = (tid & 7) * 4;
            for (int rr = tid >> 3; rr < 64; rr += 32) {
                int row = base + rr;
                float4 v = {0.f, 0.f, 0.f, 0.f};
                if (row < n) v = *(const float4*)(X + (size_t)row * K + kt * 32 + c4);
                *(float4*)(&Xs[rr][c4]) = v;
            }
        }
        {
            const float4* wsrc = (const float4*)(W + kt * 32 * 64);
            float4* wdst = (float4*)(&Ws[0][0]);
            wdst[tid] = wsrc[tid];
            wdst[tid + 256] = wsrc[tid + 256];
        }
        __syncthreads();

#pragma unroll 2
        for (int kb = 0; kb < 32; kb += 4) {
            float4 x0 = *(const float4*)(&Xs[ty * 4 + 0][kb]);
            float4 x1 = *(const float4*)(&Xs[ty * 4 + 1][kb]);
            float4 x2 = *(const float4*)(&Xs[ty * 4 + 2][kb]);
            float4 x3 = *(const float4*)(&Xs[ty * 4 + 3][kb]);
            float4 w0 = *(const float4*)(&Ws[kb + 0][tx * 4]);
            float4 w1 = *(const float4*)(&Ws[kb + 1][tx * 4]);
            float4 w2 = *(const float4*)(&Ws[kb + 2][tx * 4]);
            float4 w3 = *(const float4*)(&Ws[kb + 3][tx * 4]);
#define FMA4(i, xc, wv) \
            acc[i][0] += xc * wv.x; acc[i][1] += xc * wv.y; \
            acc[i][2] += xc * wv.z; acc[i][3] += xc * wv.w;
            FMA4(0, x0.x, w0) FMA4(0, x0.y, w1) FMA4(0, x0.z, w2) FMA4(0, x0.w, w3)
            FMA4(1, x1.x, w0) FMA4(1, x1.y, w1) FMA4(1, x1.z, w2) FMA4(1, x1.w, w3)
            FMA4(2, x2.x, w0) FMA4(2, x2.y, w1) FMA4(2, x2.z, w2) FMA4(2, x2.w, w3)
            FMA4(3, x3.x, w0) FMA4(3, x3.y, w1) FMA4(3, x3.z, w2) FMA4(3, x3.w, w3)
#undef FMA4
        }
    }

    float4 as4 = ((const float4*)a_src)[tx];
    float4 ad4 = ((const float4*)a_dst)[tx];
    int head = tx >> 2;
#pragma unroll
    for (int i = 0; i < 4; i++) {
        int node = base + ty * 4 + i;
        if (node >= n) continue;
        __half2 hlo = __floats2half2_rn(acc[i][0], acc[i][1]);
        __half2 hhi = __floats2half2_rn(acc[i][2], acc[i][3]);
        __half2* hdst = (__half2*)(&H[(size_t)node * 64 + tx * 4]);
        hdst[0] = hlo;
        hdst[1] = hhi;
        float vs = acc[i][0] * as4.x + acc[i][1] * as4.y + acc[i][2] * as4.z + acc[i][3] * as4.w;
        float vd = acc[i][0] * ad4.x + acc[i][1] * ad4.y + acc[i][2] * ad4.z + acc[i][3] * ad4.w;
        vs += __shfl_xor(vs, 1, 64); vs += __shfl_xor(vs, 2, 64);
        vd += __shfl_xor(vd, 1, 64); vd += __shfl_xor(vd, 2, 64);
        if ((tx & 3) == 0) {
            As[node * 4 + head] = vs;
            Ad[node * 4 + head] = vd;
        }
    }
}

// ---------------- fused: layer-1 GEMM (compute-bound) ∥ scatter (latency-bound) --
// The two are independent in the DAG (gemm1 needs feat/W1; scatter needs the
// CSR offsets). Gemm blocks dispatch first and fill the VALU/LDS pipes;
// scatter blocks backfill the memory pipe -> dispatch cost ~= max, not sum.
__global__ __launch_bounds__(256, 2) void gemm1_scatter_kernel(
    const float* __restrict__ X, const float* __restrict__ W,
    const float* __restrict__ a_src, const float* __restrict__ a_dst,
    __half* __restrict__ H, float* __restrict__ As, float* __restrict__ Ad, int n,
    int gemm_blocks,
    const int* __restrict__ src, const int* __restrict__ dst,
    const int* __restrict__ indptr, const int* __restrict__ rank,
    int* __restrict__ csr_src, int E)
{
    __shared__ float Xs[64][36];
    __shared__ float Ws[32][64];
    int b = blockIdx.x;
    if (b < gemm_blocks) {
        gemm_tile_body<N_FEAT_C>(X, W, a_src, a_dst, H, As, Ad, n, b, Xs, Ws);
    } else {
        int e = (b - gemm_blocks) * 256 + threadIdx.x;
        if (e < E) {
            int pos = indptr[dst[e]] + rank[e];
            atomicExch(&csr_src[pos], src[e]);
        }
    }
}

// ---------------- layer-2 GEMM (standalone) ----------------
__global__ __launch_bounds__(256, 2) void gemm_tile_kernel(
    const float* __restrict__ X, const float* __restrict__ W,
    const float* __restrict__ a_src, const float* __restrict__ a_dst,
    __half* __restrict__ H, float* __restrict__ As, float* __restrict__ Ad, int n)
{
    __shared__ float Xs[64][36];
    __shared__ float Ws[32][64];
    gemm_tile_body<N_HID_C>(X, W, a_src, a_dst, H, As, Ad, n, blockIdx.x, Xs, Ws);
}

// ---------------- fused segment-softmax + aggregation (single pass, half2) ----
// Paired-edge scheme: lanes 0-31 own cols {2lo,2lo+1} for even-slot edges,
// lanes 32-63 for odd-slot edges; combine with one shfl_xor(32) at end.
// (Round-11 lesson: no pooling fusion here -- contended atomics serialize.)
__global__ __launch_bounds__(256) void gat_aggregate(
    const __half* __restrict__ H, const float* __restrict__ As, const float* __restrict__ Ad,
    const int* __restrict__ indptr, const int* __restrict__ csr_src,
    const float* __restrict__ bias, float* __restrict__ Out, int n)
{
    __shared__ float ebuf[4][64][4];
    __shared__ int sbuf[4][64];
    int wave = threadIdx.x >> 6, lane = threadIdx.x & 63;
    int node = blockIdx.x * 4 + wave;
    if (node >= n) return;
    int p0 = indptr[node], p1 = indptr[node + 1];
    int deg = p1 - p0;
    int half = lane >> 5, lo = lane & 31;
    int head2 = lo >> 3;  // head of cols 2lo, 2lo+1
    float2 b2 = ((const float2*)bias)[lo];
    if (deg == 0) {
        if (half == 0) {
            float2 v = {fmaxf(b2.x, 0.f), fmaxf(b2.y, 0.f)};
            *(float2*)(&Out[(size_t)node * 64 + lo * 2]) = v;
        }
        return;
    }
    float4 ad4 = ((const float4*)Ad)[node];
    const __half2* H2 = (const __half2*)H;

    float accx = 0.f, accy = 0.f, denom = 0.f;
    for (int base = 0; base < deg; base += 64) {
        int p = p0 + base + lane;
        if (p < p1) {
            int s = csr_src[p];
            float4 as4 = ((const float4*)As)[s];
            ebuf[wave][lane][0] = exp2f(leaky(as4.x + ad4.x) * LOG2E_C);
            ebuf[wave][lane][1] = exp2f(leaky(as4.y + ad4.y) * LOG2E_C);
            ebuf[wave][lane][2] = exp2f(leaky(as4.z + ad4.z) * LOG2E_C);
            ebuf[wave][lane][3] = exp2f(leaky(as4.w + ad4.w) * LOG2E_C);
            sbuf[wave][lane] = s;
        }
        int cnt = min(64, deg - base);
        int j = 0;
        for (; j + 8 <= cnt; j += 8) {
            int j0 = j + half, j1 = j + 2 + half, j2 = j + 4 + half, j3 = j + 6 + half;
            float e0 = ebuf[wave][j0][head2];
            float e1 = ebuf[wave][j1][head2];
            float e2 = ebuf[wave][j2][head2];
            float e3 = ebuf[wave][j3][head2];
            int s0 = sbuf[wave][j0];
            int s1 = sbuf[wave][j1];
            int s2 = sbuf[wave][j2];
            int s3 = sbuf[wave][j3];
            __half2 h0 = H2[s0 * 32 + lo];
            __half2 h1 = H2[s1 * 32 + lo];
            __half2 h2 = H2[s2 * 32 + lo];
            __half2 h3 = H2[s3 * 32 + lo];
            denom += (e0 + e1) + (e2 + e3);
            accx += e0 * __low2float(h0);  accy += e0 * __high2float(h0);
            accx += e1 * __low2float(h1);  accy += e1 * __high2float(h1);
            accx += e2 * __low2float(h2);  accy += e2 * __high2float(h2);
            accx += e3 * __low2float(h3);  accy += e3 * __high2float(h3);
        }
        for (; j < cnt; j += 2) {
            int jA = j + half;
            if (jA < cnt) {
                float e = ebuf[wave][jA][head2];
                int s = sbuf[wave][jA];
                __half2 h = H2[s * 32 + lo];
                denom += e;
                accx += e * __low2float(h);
                accy += e * __high2float(h);
            }
        }
    }
    accx += __shfl_xor(accx, 32, 64);
    accy += __shfl_xor(accy, 32, 64);
    denom += __shfl_xor(denom, 32, 64);
    if (half == 0) {
        float inv = 1.f / (denom + 1e-16f);
        float2 v;
        v.x = fmaxf(accx * inv + b2.x, 0.f);
        v.y = fmaxf(accy * inv + b2.y, 0.f);
        *(float2*)(&Out[(size_t)node * 64 + lo * 2]) = v;
    }
}

// ---------------- pooling (run-length compressed atomics over sorted batch) --
__global__ void pool_kernel(const float* __restrict__ X, const int* __restrict__ batch,
                            float* __restrict__ sums, int n)
{
    int gw = (blockIdx.x * blockDim.x + threadIdx.x) >> 6;
    int lane = threadIdx.x & 63;
    int base = gw * 16;
    if (base >= n) return;
    int end = min(base + 16, n);
    int curg = batch[base];
    float acc = 0.f;
    for (int i = base; i < end; i++) {
        int g = batch[i];
        if (g != curg) {
            atomicAdd(&sums[curg * 64 + lane], acc);
            acc = 0.f; curg = g;
        }
        acc += X[(size_t)i * 64 + lane];
    }
    atomicAdd(&sums[curg * 64 + lane], acc);
}

// ---------------- final FC (per-graph counts via binary search on sorted batch) --
__global__ void fc_kernel(const float* __restrict__ sums, const int* __restrict__ batch,
                          const float* __restrict__ fcW, const float* __restrict__ fcb,
                          float* __restrict__ out, int n)
{
    __shared__ int lower[NUM_GRAPHS_C + 1];
    int t = threadIdx.x;
    if (t <= NUM_GRAPHS_C) {
        int lo = 0, hi = n;
        while (lo < hi) {
            int mid = (lo + hi) >> 1;
            if (batch[mid] < t) lo = mid + 1; else hi = mid;
        }
        lower[t] = lo;
    }
    __syncthreads();
    if (t >= NUM_GRAPHS_C * N_CLASS_C) return;
    int g = t / N_CLASS_C, c = t % N_CLASS_C;
    float cnt = fmaxf((float)(lower[g + 1] - lower[g]), 1.f);
    float inv = 1.f / cnt;
    float acc = fcb[c];
    for (int k = 0; k < 64; k++)
        acc += (sums[g * 64 + k] * inv) * fcW[k * N_CLASS_C + c];
    out[g * N_CLASS_C + c] = acc;
}

extern "C" void kernel_launch(void* const* d_in, const int* in_sizes, int n_in,
                              void* d_out, int out_size, void* d_ws, size_t ws_size,
                              hipStream_t stream) {
    const float* feat = (const float*)d_in[0];
    const float* W1   = (const float*)d_in[1];
    const float* a1s  = (const float*)d_in[2];
    const float* a1d  = (const float*)d_in[3];
    const float* b1   = (const float*)d_in[4];
    const float* W2   = (const float*)d_in[5];
    const float* a2s  = (const float*)d_in[6];
    const float* a2d  = (const float*)d_in[7];
    const float* b2   = (const float*)d_in[8];
    const float* fcW  = (const float*)d_in[9];
    const float* fcb  = (const float*)d_in[10];
    const int* eidx   = (const int*)d_in[11];
    const int* batch  = (const int*)d_in[12];

    const int N = N_NODES_C;
    const int E = N_EDGES_C;
    const int* src = eidx;
    const int* dst = eidx + E;

    char* ws = (char*)d_ws;
    size_t off = 0;
    auto alloc = [&](size_t bytes) -> void* {
        void* p = ws + off;
        off += (bytes + 255) & ~(size_t)255;
        return p;
    };
    __half* h      = (__half*)alloc((size_t)N * 64 * 2);
    float* outb    = (float*)alloc((size_t)N * 64 * 4);
    float* As      = (float*)alloc((size_t)N * 4 * 4);
    float* Ad      = (float*)alloc((size_t)N * 4 * 4);
    int*   indptr  = (int*)alloc((size_t)(N + 1) * 4);
    int*   counts  = (int*)alloc((size_t)N * 4);
    int*   rank    = (int*)alloc((size_t)E * 4);
    int*   csr_src = (int*)alloc((size_t)E * 4);
    int*   bsum    = (int*)alloc(64 * 4);
    float* sums    = (float*)alloc((size_t)NUM_GRAPHS_C * 64 * 4);

    const int NB = (N + 1023) / 1024;  // 49
    const int GEMM_BLOCKS = (N + 63) / 64;  // 782
    const int SCAT_BLOCKS = (E + 255) / 256;  // 3125
    const int AGG_BLOCKS = (N + 3) / 4;

    // CSR build (graph identical for both layers)
    zero_kernel<<<(N + 255) / 256, 256, 0, stream>>>(counts, sums, N);
    count_rank_kernel<<<SCAT_BLOCKS, 256, 0, stream>>>(dst, counts, rank, E);
    scan_part<<<NB, 256, 0, stream>>>(counts, bsum, N);
    scan_block<<<NB, 256, 0, stream>>>(counts, bsum, indptr, N, NB);

    // layer-1 GEMM (independent of CSR) fused with scatter: compute ∥ latency
    gemm1_scatter_kernel<<<GEMM_BLOCKS + SCAT_BLOCKS, 256, 0, stream>>>(
        feat, W1, a1s, a1d, h, As, Ad, N, GEMM_BLOCKS,
        src, dst, indptr, rank, csr_src, E);

    gat_aggregate<<<AGG_BLOCKS, 256, 0, stream>>>(h, As, Ad, indptr, csr_src, b1, outb, N);
    // layer 2
    gemm_tile_kernel<<<GEMM_BLOCKS, 256, 0, stream>>>(outb, W2, a2s, a2d, h, As, Ad, N);
    gat_aggregate<<<AGG_BLOCKS, 256, 0, stream>>>(h, As, Ad, indptr, csr_src, b2, outb, N);

    // pool + fc (counts via binary search on the sorted batch vector)
    int pool_waves = (N + 15) / 16;
    pool_kernel<<<(pool_waves * 64 + 255) / 256, 256, 0, stream>>>(outb, batch, sums, N);
    fc_kernel<<<1, 1024, 0, stream>>>(sums, batch, fcW, fcb, (float*)d_out, N);
}

// Round 14
// 170.697 us; speedup vs baseline: 1.7636x; 1.0183x over previous
//
#include <hip/hip_runtime.h>
#include <hip/hip_fp16.h>
#include <cmath>

#define N_NODES_C 50000
#define N_EDGES_C 800000
#define N_FEAT_C 128
#define N_HID_C 64
#define HEADS_C 4
#define HEAD_DIM_C 16
#define N_CLASS_C 10
#define NUM_GRAPHS_C 64
#define LOG2E_C 1.44269504088896340736f

static __device__ __forceinline__ float leaky(float x) { return x > 0.f ? x : 0.2f * x; }

// ---------------- init ----------------
__global__ void zero_kernel(int* counts, float* sums, int n) {
    int i = blockIdx.x * blockDim.x + threadIdx.x;
    if (i < n) counts[i] = 0;
    if (i < NUM_GRAPHS_C * N_HID_C) sums[i] = 0.f;
}

// count incoming edges per dst AND record each edge's arrival rank.
__global__ void count_rank_kernel(const int* __restrict__ dst, int* __restrict__ counts,
                                  int* __restrict__ rank, int E) {
    int e = blockIdx.x * blockDim.x + threadIdx.x;
    if (e < E) rank[e] = atomicAdd(&counts[dst[e]], 1);
}

// ---------------- hierarchical scan: counts -> indptr ----------------
__global__ void scan_part(const int* __restrict__ counts, int* __restrict__ bsum, int n) {
    int b = blockIdx.x, t = threadIdx.x;  // 256 threads
    int base = b * 1024 + t * 4;
    int v = 0;
    if (base + 3 < n) {
        int4 c = *(const int4*)(counts + base);
        v = c.x + c.y + c.z + c.w;
    } else {
        for (int i = 0; i < 4; i++) if (base + i < n) v += counts[base + i];
    }
    for (int off = 32; off; off >>= 1) v += __shfl_xor(v, off, 64);
    __shared__ int ws[4];
    if ((t & 63) == 0) ws[t >> 6] = v;
    __syncthreads();
    if (t == 0) bsum[b] = ws[0] + ws[1] + ws[2] + ws[3];
}

// per-block scan; block offset computed inline by reducing bsum[0..b)
__global__ void scan_block(const int* __restrict__ counts, const int* __restrict__ bsum,
                           int* __restrict__ indptr, int n, int nb) {
    int b = blockIdx.x, t = threadIdx.x;  // 256 threads
    __shared__ int boff_s;
    if (t < 64) {
        int v = (t < b && t < nb) ? bsum[t] : 0;
        for (int off = 32; off; off >>= 1) v += __shfl_xor(v, off, 64);
        if (t == 0) boff_s = v;
    }
    int base = b * 1024 + t * 4;
    int4 c = {0, 0, 0, 0};
    if (base + 3 < n) c = *(const int4*)(counts + base);
    else {
        if (base + 0 < n) c.x = counts[base + 0];
        if (base + 1 < n) c.y = counts[base + 1];
        if (base + 2 < n) c.z = counts[base + 2];
        if (base + 3 < n) c.w = counts[base + 3];
    }
    int s0 = c.x, s1 = s0 + c.y, s2 = s1 + c.z, s3 = s2 + c.w;
    int tsum = s3;
    int lane = t & 63, wv = t >> 6;
    int v = tsum;
    for (int off = 1; off < 64; off <<= 1) {
        int u = __shfl_up(v, off, 64);
        if (lane >= off) v += u;
    }
    __shared__ int wsum[4];
    if (lane == 63) wsum[wv] = v;
    __syncthreads();
    int woff = 0;
    for (int w = 0; w < wv; w++) woff += wsum[w];
    int excl = v - tsum + woff + boff_s;
    if (b == 0 && t == 0) indptr[0] = 0;
    if (base + 0 < n) indptr[base + 1] = excl + s0;
    if (base + 1 < n) indptr[base + 2] = excl + s1;
    if (base + 2 < n) indptr[base + 3] = excl + s2;
    if (base + 3 < n) indptr[base + 4] = excl + s3;
}

// ---------------- GEMM tile body (templated on input dtype) ----------------
// 2-LDS-tile, 4x4 micro-tile. kt unroll 1 + kb unroll 2 keeps in-flight
// ds_reads bounded (round-6 full unroll caused VGPR exhaustion + spill).
// X may be fp32 (layer 1: feat) or fp16 (layer 2: prev activations) --
// staging converts to fp32 in LDS so the tuned compute loop is unchanged.
template <int K, typename XT>
static __device__ __forceinline__ void gemm_tile_body(
    const XT* __restrict__ X, const float* __restrict__ W,
    const float* __restrict__ a_src, const float* __restrict__ a_dst,
    __half* __restrict__ H, float* __restrict__ As, float* __restrict__ Ad,
    int n, int blk, float (*Xs)[36], float (*Ws)[64])
{
    int tid = threadIdx.x;
    int tx = tid & 15, ty = tid >> 4;
    int base = blk * 64;

    float acc[4][4];
#pragma unroll
    for (int i = 0; i < 4; i++)
#pragma unroll
        for (int j = 0; j < 4; j++) acc[i][j] = 0.f;

#pragma unroll 1
    for (int kt = 0; kt < K / 32; kt++) {
        if (kt > 0) __syncthreads();
        {
            int c4 = (tid & 7) * 4;
            for (int rr = tid >> 3; rr < 64; rr += 32) {
                int row = base + rr;
                float4 v = {0.f, 0.f, 0.f, 0.f};
                if (row < n) {
                    if constexpr (sizeof(XT) == 4) {
                        v = *(const float4*)((const float*)X + (size_t)row * K + kt * 32 + c4);
                    } else {
                        const __half2* hp = (const __half2*)((const __half*)X + (size_t)row * K + kt * 32 + c4);
                        float2 fa = __half22float2(hp[0]);
                        float2 fb = __half22float2(hp[1]);
                        v = make_float4(fa.x, fa.y, fb.x, fb.y);
                    }
                }
                *(float4*)(&Xs[rr][c4]) = v;
            }
        }
        {
            const float4* wsrc = (const float4*)(W + kt * 32 * 64);
            float4* wdst = (float4*)(&Ws[0][0]);
            wdst[tid] = wsrc[tid];
            wdst[tid + 256] = wsrc[tid + 256];
        }
        __syncthreads();

#pragma unroll 2
        for (int kb = 0; kb < 32; kb += 4) {
            float4 x0 = *(const float4*)(&Xs[ty * 4 + 0][kb]);
            float4 x1 = *(const float4*)(&Xs[ty * 4 + 1][kb]);
            float4 x2 = *(const float4*)(&Xs[ty * 4 + 2][kb]);
            float4 x3 = *(const float4*)(&Xs[ty * 4 + 3][kb]);
            float4 w0 = *(const float4*)(&Ws[kb + 0][tx * 4]);
            float4 w1 = *(const float4*)(&Ws[kb + 1][tx * 4]);
            float4 w2 = *(const float4*)(&Ws[kb + 2][tx * 4]);
            float4 w3 = *(const float4*)(&Ws[kb + 3][tx * 4]);
#define FMA4(i, xc, wv) \
            acc[i][0] += xc * wv.x; acc[i][1] += xc * wv.y; \
            acc[i][2] += xc * wv.z; acc[i][3] += xc * wv.w;
            FMA4(0, x0.x, w0) FMA4(0, x0.y, w1) FMA4(0, x0.z, w2) FMA4(0, x0.w, w3)
            FMA4(1, x1.x, w0) FMA4(1, x1.y, w1) FMA4(1, x1.z, w2) FMA4(1, x1.w, w3)
            FMA4(2, x2.x, w0) FMA4(2, x2.y, w1) FMA4(2, x2.z, w2) FMA4(2, x2.w, w3)
            FMA4(3, x3.x, w0) FMA4(3, x3.y, w1) FMA4(3, x3.z, w2) FMA4(3, x3.w, w3)
#undef FMA4
        }
    }

    float4 as4 = ((const float4*)a_src)[tx];
    float4 ad4 = ((const float4*)a_dst)[tx];
    int head = tx >> 2;
#pragma unroll
    for (int i = 0; i < 4; i++) {
        int node = base + ty * 4 + i;
        if (node >= n) continue;
        __half2 hlo = __floats2half2_rn(acc[i][0], acc[i][1]);
        __half2 hhi = __floats2half2_rn(acc[i][2], acc[i][3]);
        __half2* hdst = (__half2*)(&H[(size_t)node * 64 + tx * 4]);
        hdst[0] = hlo;
        hdst[1] = hhi;
        float vs = acc[i][0] * as4.x + acc[i][1] * as4.y + acc[i][2] * as4.z + acc[i][3] * as4.w;
        float vd = acc[i][0] * ad4.x + acc[i][1] * ad4.y + acc[i][2] * ad4.z + acc[i][3] * ad4.w;
        vs += __shfl_xor(vs, 1, 64); vs += __shfl_xor(vs, 2, 64);
        vd += __shfl_xor(vd, 1, 64); vd += __shfl_xor(vd, 2, 64);
        if ((tx & 3) == 0) {
            As[node * 4 + head] = vs;
            Ad[node * 4 + head] = vd;
        }
    }
}

// ---------------- fused: layer-1 GEMM (compute-bound) ∥ scatter (latency-bound) --
__global__ __launch_bounds__(256, 2) void gemm1_scatter_kernel(
    const float* __restrict__ X, const float* __restrict__ W,
    const float* __restrict__ a_src, const float* __restrict__ a_dst,
    __half* __restrict__ H, float* __restrict__ As, float* __restrict__ Ad, int n,
    int gemm_blocks,
    const int* __restrict__ src, const int* __restrict__ dst,
    const int* __restrict__ indptr, const int* __restrict__ rank,
    int* __restrict__ csr_src, int E)
{
    __shared__ float Xs[64][36];
    __shared__ float Ws[32][64];
    int b = blockIdx.x;
    if (b < gemm_blocks) {
        gemm_tile_body<N_FEAT_C, float>(X, W, a_src, a_dst, H, As, Ad, n, b, Xs, Ws);
    } else {
        int e = (b - gemm_blocks) * 256 + threadIdx.x;
        if (e < E) {
            int pos = indptr[dst[e]] + rank[e];
            atomicExch(&csr_src[pos], src[e]);
        }
    }
}

// ---------------- layer-2 GEMM (fp16 input) ----------------
__global__ __launch_bounds__(256, 2) void gemm_tile_kernel(
    const __half* __restrict__ X, const float* __restrict__ W,
    const float* __restrict__ a_src, const float* __restrict__ a_dst,
    __half* __restrict__ H, float* __restrict__ As, float* __restrict__ Ad, int n)
{
    __shared__ float Xs[64][36];
    __shared__ float Ws[32][64];
    gemm_tile_body<N_HID_C, __half>(X, W, a_src, a_dst, H, As, Ad, n, blockIdx.x, Xs, Ws);
}

// ---------------- fused segment-softmax + aggregation (single pass, half2) ----
// Paired-edge scheme: lanes 0-31 own cols {2lo,2lo+1} for even-slot edges,
// lanes 32-63 for odd-slot edges; combine with one shfl_xor(32) at end.
// Output written as fp16 (halves write traffic; consumer is gemm2/pool).
// (Round-11 lesson: no pooling fusion here -- contended atomics serialize.)
__global__ __launch_bounds__(256) void gat_aggregate(
    const __half* __restrict__ H, const float* __restrict__ As, const float* __restrict__ Ad,
    const int* __restrict__ indptr, const int* __restrict__ csr_src,
    const float* __restrict__ bias, __half* __restrict__ Out, int n)
{
    __shared__ float ebuf[4][64][4];
    __shared__ int sbuf[4][64];
    int wave = threadIdx.x >> 6, lane = threadIdx.x & 63;
    int node = blockIdx.x * 4 + wave;
    if (node >= n) return;
    int p0 = indptr[node], p1 = indptr[node + 1];
    int deg = p1 - p0;
    int half = lane >> 5, lo = lane & 31;
    int head2 = lo >> 3;  // head of cols 2lo, 2lo+1
    float2 b2 = ((const float2*)bias)[lo];
    __half2* Out2 = (__half2*)Out;
    if (deg == 0) {
        if (half == 0)
            Out2[(size_t)node * 32 + lo] = __floats2half2_rn(fmaxf(b2.x, 0.f), fmaxf(b2.y, 0.f));
        return;
    }
    float4 ad4 = ((const float4*)Ad)[node];
    const __half2* H2 = (const __half2*)H;

    float accx = 0.f, accy = 0.f, denom = 0.f;
    for (int base = 0; base < deg; base += 64) {
        int p = p0 + base + lane;
        if (p < p1) {
            int s = csr_src[p];
            float4 as4 = ((const float4*)As)[s];
            ebuf[wave][lane][0] = exp2f(leaky(as4.x + ad4.x) * LOG2E_C);
            ebuf[wave][lane][1] = exp2f(leaky(as4.y + ad4.y) * LOG2E_C);
            ebuf[wave][lane][2] = exp2f(leaky(as4.z + ad4.z) * LOG2E_C);
            ebuf[wave][lane][3] = exp2f(leaky(as4.w + ad4.w) * LOG2E_C);
            sbuf[wave][lane] = s;
        }
        int cnt = min(64, deg - base);
        int j = 0;
        for (; j + 8 <= cnt; j += 8) {
            int j0 = j + half, j1 = j + 2 + half, j2 = j + 4 + half, j3 = j + 6 + half;
            float e0 = ebuf[wave][j0][head2];
            float e1 = ebuf[wave][j1][head2];
            float e2 = ebuf[wave][j2][head2];
            float e3 = ebuf[wave][j3][head2];
            int s0 = sbuf[wave][j0];
            int s1 = sbuf[wave][j1];
            int s2 = sbuf[wave][j2];
            int s3 = sbuf[wave][j3];
            __half2 h0 = H2[s0 * 32 + lo];
            __half2 h1 = H2[s1 * 32 + lo];
            __half2 h2 = H2[s2 * 32 + lo];
            __half2 h3 = H2[s3 * 32 + lo];
            denom += (e0 + e1) + (e2 + e3);
            accx += e0 * __low2float(h0);  accy += e0 * __high2float(h0);
            accx += e1 * __low2float(h1);  accy += e1 * __high2float(h1);
            accx += e2 * __low2float(h2);  accy += e2 * __high2float(h2);
            accx += e3 * __low2float(h3);  accy += e3 * __high2float(h3);
        }
        if (j + 4 <= cnt) {
            int j0 = j + half, j1 = j + 2 + half;
            float e0 = ebuf[wave][j0][head2];
            float e1 = ebuf[wave][j1][head2];
            int s0 = sbuf[wave][j0];
            int s1 = sbuf[wave][j1];
            __half2 h0 = H2[s0 * 32 + lo];
            __half2 h1 = H2[s1 * 32 + lo];
            denom += e0 + e1;
            accx += e0 * __low2float(h0);  accy += e0 * __high2float(h0);
            accx += e1 * __low2float(h1);  accy += e1 * __high2float(h1);
            j += 4;
        }
        for (; j < cnt; j += 2) {
            int jA = j + half;
            if (jA < cnt) {
                float e = ebuf[wave][jA][head2];
                int s = sbuf[wave][jA];
                __half2 h = H2[s * 32 + lo];
                denom += e;
                accx += e * __low2float(h);
                accy += e * __high2float(h);
            }
        }
    }
    accx += __shfl_xor(accx, 32, 64);
    accy += __shfl_xor(accy, 32, 64);
    denom += __shfl_xor(denom, 32, 64);
    if (half == 0) {
        float inv = 1.f / (denom + 1e-16f);
        float vx = fmaxf(accx * inv + b2.x, 0.f);
        float vy = fmaxf(accy * inv + b2.y, 0.f);
        Out2[(size_t)node * 32 + lo] = __floats2half2_rn(vx, vy);
    }
}

// ---------------- pooling (run-length compressed atomics over sorted batch) --
__global__ void pool_kernel(const __half* __restrict__ X, const int* __restrict__ batch,
                            float* __restrict__ sums, int n)
{
    int gw = (blockIdx.x * blockDim.x + threadIdx.x) >> 6;
    int lane = threadIdx.x & 63;
    int base = gw * 16;
    if (base >= n) return;
    int end = min(base + 16, n);
    int curg = batch[base];
    float acc = 0.f;
    for (int i = base; i < end; i++) {
        int g = batch[i];
        if (g != curg) {
            atomicAdd(&sums[curg * 64 + lane], acc);
            acc = 0.f; curg = g;
        }
        acc += __half2float(X[(size_t)i * 64 + lane]);
    }
    atomicAdd(&sums[curg * 64 + lane], acc);
}

// ---------------- final FC (per-graph counts via binary search on sorted batch) --
__global__ void fc_kernel(const float* __restrict__ sums, const int* __restrict__ batch,
                          const float* __restrict__ fcW, const float* __restrict__ fcb,
                          float* __restrict__ out, int n)
{
    __shared__ int lower[NUM_GRAPHS_C + 1];
    int t = threadIdx.x;
    if (t <= NUM_GRAPHS_C) {
        int lo = 0, hi = n;
        while (lo < hi) {
            int mid = (lo + hi) >> 1;
            if (batch[mid] < t) lo = mid + 1; else hi = mid;
        }
        lower[t] = lo;
    }
    __syncthreads();
    if (t >= NUM_GRAPHS_C * N_CLASS_C) return;
    int g = t / N_CLASS_C, c = t % N_CLASS_C;
    float cnt = fmaxf((float)(lower[g + 1] - lower[g]), 1.f);
    float inv = 1.f / cnt;
    float acc = fcb[c];
    for (int k = 0; k < 64; k++)
        acc += (sums[g * 64 + k] * inv) * fcW[k * N_CLASS_C + c];
    out[g * N_CLASS_C + c] = acc;
}

extern "C" void kernel_launch(void* const* d_in, const int* in_sizes, int n_in,
                              void* d_out, int out_size, void* d_ws, size_t ws_size,
                              hipStream_t stream) {
    const float* feat = (const float*)d_in[0];
    const float* W1   = (const float*)d_in[1];
    const float* a1s  = (const float*)d_in[2];
    const float* a1d  = (const float*)d_in[3];
    const float* b1   = (const float*)d_in[4];
    const float* W2   = (const float*)d_in[5];
    const float* a2s  = (const float*)d_in[6];
    const float* a2d  = (const float*)d_in[7];
    const float* b2   = (const float*)d_in[8];
    const float* fcW  = (const float*)d_in[9];
    const float* fcb  = (const float*)d_in[10];
    const int* eidx   = (const int*)d_in[11];
    const int* batch  = (const int*)d_in[12];

    const int N = N_NODES_C;
    const int E = N_EDGES_C;
    const int* src = eidx;
    const int* dst = eidx + E;

    char* ws = (char*)d_ws;
    size_t off = 0;
    auto alloc = [&](size_t bytes) -> void* {
        void* p = ws + off;
        off += (bytes + 255) & ~(size_t)255;
        return p;
    };
    __half* h      = (__half*)alloc((size_t)N * 64 * 2);
    __half* outh   = (__half*)alloc((size_t)N * 64 * 2);
    float* As      = (float*)alloc((size_t)N * 4 * 4);
    float* Ad      = (float*)alloc((size_t)N * 4 * 4);
    int*   indptr  = (int*)alloc((size_t)(N + 1) * 4);
    int*   counts  = (int*)alloc((size_t)N * 4);
    int*   rank    = (int*)alloc((size_t)E * 4);
    int*   csr_src = (int*)alloc((size_t)E * 4);
    int*   bsum    = (int*)alloc(64 * 4);
    float* sums    = (float*)alloc((size_t)NUM_GRAPHS_C * 64 * 4);

    const int NB = (N + 1023) / 1024;  // 49
    const int GEMM_BLOCKS = (N + 63) / 64;  // 782
    const int SCAT_BLOCKS = (E + 255) / 256;  // 3125
    const int AGG_BLOCKS = (N + 3) / 4;

    // CSR build (graph identical for both layers)
    zero_kernel<<<(N + 255) / 256, 256, 0, stream>>>(counts, sums, N);
    count_rank_kernel<<<SCAT_BLOCKS, 256, 0, stream>>>(dst, counts, rank, E);
    scan_part<<<NB, 256, 0, stream>>>(counts, bsum, N);
    scan_block<<<NB, 256, 0, stream>>>(counts, bsum, indptr, N, NB);

    // layer-1 GEMM (independent of CSR) fused with scatter: compute ∥ latency
    gemm1_scatter_kernel<<<GEMM_BLOCKS + SCAT_BLOCKS, 256, 0, stream>>>(
        feat, W1, a1s, a1d, h, As, Ad, N, GEMM_BLOCKS,
        src, dst, indptr, rank, csr_src, E);

    gat_aggregate<<<AGG_BLOCKS, 256, 0, stream>>>(h, As, Ad, indptr, csr_src, b1, outh, N);
    // layer 2 (fp16 activations in)
    gemm_tile_kernel<<<GEMM_BLOCKS, 256, 0, stream>>>(outh, W2, a2s, a2d, h, As, Ad, N);
    gat_aggregate<<<AGG_BLOCKS, 256, 0, stream>>>(h, As, Ad, indptr, csr_src, b2, outh, N);

    // pool + fc (counts via binary search on the sorted batch vector)
    int pool_waves = (N + 15) / 16;
    pool_kernel<<<(pool_waves * 64 + 255) / 256, 256, 0, stream>>>(outh, batch, sums, N);
    fc_kernel<<<1, 1024, 0, stream>>>(sums, batch, fcW, fcb, (float*)d_out, N);
}